// Round 9
// baseline (219.605 us; speedup 1.0000x reference)
//
#include <hip/hip_runtime.h>
#include <hip/hip_bf16.h>
#include <string.h>

#define BB 4
#define CPc 256
#define NN 2304   // 48*48

typedef __attribute__((ext_vector_type(8))) short bf16x8;
typedef __attribute__((ext_vector_type(4))) float f32x4;

__device__ __forceinline__ short f2b(float x) {
    __hip_bfloat16 h = __float2bfloat16(x);
    return *reinterpret_cast<short*>(&h);
}
__device__ __forceinline__ float b2f16(short v) {
    union { float f; unsigned u; } x;
    x.u = ((unsigned)(unsigned short)v) << 16;
    return x.f;
}

// load 8 consecutive f32, convert to a bf16x8 fragment (RNE)
__device__ __forceinline__ bf16x8 ld8cvt(const float* p) {
    const float4 a = *(const float4*)p;
    const float4 b = *(const float4*)(p + 4);
    bf16x8 r;
    r[0] = f2b(a.x); r[1] = f2b(a.y); r[2] = f2b(a.z); r[3] = f2b(a.w);
    r[4] = f2b(b.x); r[5] = f2b(b.y); r[6] = f2b(b.z); r[7] = f2b(b.w);
    return r;
}

// async global->LDS DMA, 16B per lane, dest = uniform base + lane*16
__device__ __forceinline__ void gl2lds16(const void* g, void* l) {
    __builtin_amdgcn_global_load_lds(
        (const __attribute__((address_space(1))) void*)g,
        (__attribute__((address_space(3))) void*)l, 16, 0, 0);
}

// ---------------- K0: convert CONV weights fp32 -> bf16 ----------------------
// grid = (16384 + 2*249856)/256 = 2016
__global__ __launch_bounds__(256) void k_wcvt(
    const float* __restrict__ t_w,
    const float* p0, const float* p1, const float* p2, const float* p3, const float* p4,
    const float* g0, const float* g1, const float* g2, const float* g3, const float* g4,
    short* __restrict__ TWb, short* __restrict__ WPb, short* __restrict__ WGb) {
    int idx = blockIdx.x * 256 + threadIdx.x;
    if (idx < 16384) { TWb[idx] = f2b(t_w[idx]); return; }
    int k = idx - 16384;
    bool isP = k < 249856;
    if (!isP) k -= 249856;
    int i, off;
    if (k < 4096)        { i = 0; off = 0; }
    else if (k < 20480)  { i = 1; off = 4096; }
    else if (k < 53248)  { i = 2; off = 20480; }
    else if (k < 118784) { i = 3; off = 53248; }
    else                 { i = 4; off = 118784; }
    const float* s;
    if (isP) s = (i == 0) ? p0 : (i == 1) ? p1 : (i == 2) ? p2 : (i == 3) ? p3 : p4;
    else     s = (i == 0) ? g0 : (i == 1) ? g1 : (i == 2) ? g2 : (i == 3) ? g3 : g4;
    (isP ? WPb : WGb)[k] = f2b(s[k - off]);
}

// ---------------- K1: batched MFMA 1x1 convs — UNIFORM 2-CHUNK SPLIT-K --------
// R9: k_conv was latency-bound (R7 PMC: MfmaUtil 1.2%, 12.6% occ) with 584
// blocks (2.3/CU) each a 4-chunk serial chain of exposed HBM latency. Now ALL
// segments are split so every block runs at most 2 chunks: seg0/2 KS=2 (seg0
// gains a TQ-partial path), seg3/4/5 KS=4/8/16. Grid 1024 (4/CU). k_cvt sums
// all partials. f32-reassociation only (f2b after full sum, as before).
__global__ __launch_bounds__(256) void k_conv(
    const float* __restrict__ persp,
    const float* r0, const float* r1, const float* r2, const float* r3, const float* r4,
    const short* __restrict__ TWb, const short* __restrict__ WPb, const short* __restrict__ WGb,
    short* __restrict__ PTb, short* __restrict__ GTb,
    float* __restrict__ PPART, float* __restrict__ GPART) {
    const int CUM[7]  = {0, 288, 432, 720, 864, 960, 1024};
    const int CRs[6]  = {256, 64, 256, 512, 1024, 2048};
    const int Mus[6]  = {2304, 2304, 2304, 576, 144, 36};
    const int Mps[6]  = {2304, 2304, 2304, 576, 192, 64};
    const int KSs[6]  = {2, 1, 2, 4, 8, 16};
    const int WOFF[6] = {0, 0, 4096, 20480, 53248, 118784};
    const int POFF[6] = {0, 0, 589824, 1179648, 1327104, 1376256};
    const int PBASE[6] = {0, 0, 1179648, 2359296, 2949120, 3342336};  // into PPART
    const int GBASE[6] = {0, 0, 0, 1179648, 1769472, 2162688};        // into GPART

    __shared__ __align__(16) short s_a[2][64][72];

    int blk = blockIdx.x, t = threadIdx.x;
    int w = t >> 6, lane = t & 63, lo = lane & 15, quad = lane >> 4;
    int seg = 0;
#pragma unroll
    for (int s_ = 1; s_ <= 5; ++s_) if (blk >= CUM[s_]) seg = s_;
    int Cr = CRs[seg], M = Mus[seg], Mp = Mps[seg], KS = KSs[seg];
    const float* in = (seg == 0) ? persp : (seg == 1) ? r0 : (seg == 2) ? r1 :
                      (seg == 3) ? r2 : (seg == 4) ? r3 : r4;
    const short* wp = (seg == 0) ? TWb : WPb + WOFF[seg];
    const short* wg = WGb + WOFF[seg];
    bool has_g = (seg != 0);
    int local = blk - CUM[seg];
    int mt = Mp >> 6;
    int b = local / (mt * KS);
    int rem = local % (mt * KS);
    int m0 = (rem / KS) * 64;
    int ksi = rem % KS;
    int kLen = Cr / KS, k0 = ksi * kLen;

    int ml = t & 63;
    int ssw = (ml >> 3) & 7;
    bool mvalid = (m0 + ml) < M;
    const float* inB = in + ((size_t)b * Cr) * M + m0 + ml;

    int mrow = w * 16 + lo;
    int rsw = (mrow >> 3) & 7;

    f32x4 accP[4], accG[4];
#pragma unroll
    for (int ct = 0; ct < 4; ++ct) {
        accP[ct] = f32x4{0.f, 0.f, 0.f, 0.f};
        accG[ct] = f32x4{0.f, 0.f, 0.f, 0.f};
    }

    float pv0[8], pv1[8];
#define LOADCH(KC)                                                              \
    {                                                                           \
        _Pragma("unroll")                                                       \
        for (int r = 0; r < 8; ++r) {                                           \
            int kp = w + r * 4;                                                 \
            pv0[r] = 0.f; pv1[r] = 0.f;                                         \
            if (mvalid) {                                                       \
                pv0[r] = inB[(size_t)((KC) + 2 * kp) * M];                      \
                pv1[r] = inB[(size_t)((KC) + 2 * kp + 1) * M];                  \
            }                                                                   \
        }                                                                       \
    }
#define WRITECH(BUF)                                                            \
    {                                                                           \
        _Pragma("unroll")                                                       \
        for (int r = 0; r < 8; ++r) {                                           \
            int kp = w + r * 4;                                                 \
            int q = kp >> 2, l = kp & 3;                                        \
            short2 pk; pk.x = f2b(pv0[r]); pk.y = f2b(pv1[r]);                  \
            *(short2*)&s_a[BUF][ml][(q ^ ssw) * 8 + l * 2] = pk;                \
        }                                                                       \
    }

    // prologue: stage chunk 0
    LOADCH(k0);
    WRITECH(0);
    __syncthreads();

    int cur = 0;
    for (int kc = k0; kc < k0 + kLen; kc += 64) {
        bool more = (kc + 64) < (k0 + kLen);
        if (more) LOADCH(kc + 64);   // issue next chunk's inputs early

        // weight fragments for this chunk (bf16, L2-hot; overlap with ds_reads)
        bf16x8 wf0[4], wf1[4], wg0[4], wg1[4];
#pragma unroll
        for (int ct = 0; ct < 4; ++ct) {
            wf0[ct] = *(const bf16x8*)&wp[(size_t)(ct * 16 + lo) * Cr + kc + quad * 8];
            wf1[ct] = *(const bf16x8*)&wp[(size_t)(ct * 16 + lo) * Cr + kc + 32 + quad * 8];
            if (has_g) {
                wg0[ct] = *(const bf16x8*)&wg[(size_t)(ct * 16 + lo) * Cr + kc + quad * 8];
                wg1[ct] = *(const bf16x8*)&wg[(size_t)(ct * 16 + lo) * Cr + kc + 32 + quad * 8];
            }
        }
        const bf16x8 fr0 = *(const bf16x8*)&s_a[cur][mrow][8 * (quad ^ rsw)];
        const bf16x8 fr1 = *(const bf16x8*)&s_a[cur][mrow][8 * ((4 + quad) ^ rsw)];
#pragma unroll
        for (int ct = 0; ct < 4; ++ct) {
            accP[ct] = __builtin_amdgcn_mfma_f32_16x16x32_bf16(fr0, wf0[ct], accP[ct], 0, 0, 0);
            accP[ct] = __builtin_amdgcn_mfma_f32_16x16x32_bf16(fr1, wf1[ct], accP[ct], 0, 0, 0);
            if (has_g) {
                accG[ct] = __builtin_amdgcn_mfma_f32_16x16x32_bf16(wg0[ct], fr0, accG[ct], 0, 0, 0);
                accG[ct] = __builtin_amdgcn_mfma_f32_16x16x32_bf16(wg1[ct], fr1, accG[ct], 0, 0, 0);
            }
        }
        if (more) WRITECH(cur ^ 1);  // vmcnt wait lands here, after MFMA
        __syncthreads();             // one barrier per chunk
        cur ^= 1;
    }
#undef LOADCH
#undef WRITECH

    if (KS == 1) {   // seg1 only
        short* outP = PTb + POFF[seg];
        short* outG = GTb + POFF[seg];
        int mP = m0 + w * 16 + quad * 4;
#pragma unroll
        for (int ct = 0; ct < 4; ++ct) {
            int c = ct * 16 + lo;
#pragma unroll
            for (int rg = 0; rg < 4; ++rg)
                outP[((size_t)b * Mp + mP + rg) * 64 + c] = f2b(accP[ct][rg]);
        }
        int mG = m0 + w * 16 + lo;
#pragma unroll
        for (int ct = 0; ct < 4; ++ct) {
            int cG = ct * 16 + quad * 4;
#pragma unroll
            for (int rg = 0; rg < 4; ++rg)
                outG[((size_t)b * 64 + cG + rg) * Mp + mG] = f2b(accG[ct][rg]);
        }
    } else {
        int NP = 4 * Mp * 64;
        float* pp = PPART + PBASE[seg] + (size_t)ksi * NP;
        int mP = m0 + w * 16 + quad * 4;
#pragma unroll
        for (int ct = 0; ct < 4; ++ct) {
            int c = ct * 16 + lo;
#pragma unroll
            for (int rg = 0; rg < 4; ++rg)
                pp[((size_t)b * Mp + mP + rg) * 64 + c] = accP[ct][rg];
        }
        if (has_g) {
            float* gp = GPART + GBASE[seg] + (size_t)ksi * NP;
            int mG = m0 + w * 16 + lo;
#pragma unroll
            for (int ct = 0; ct < 4; ++ct) {
                int cG = ct * 16 + quad * 4;
#pragma unroll
                for (int rg = 0; rg < 4; ++rg)
                    gp[((size_t)b * 64 + cG + rg) * Mp + mG] = accG[ct][rg];
            }
        }
    }
}

// ---------------- K1b: reduce split-K partials -> bf16 TQb/PTb/GTb ------------
// grid = (589824 + 802816)/256 = 5440
__global__ __launch_bounds__(256) void k_cvt(const float* __restrict__ PPART,
                                             const float* __restrict__ GPART,
                                             short* __restrict__ TQb,
                                             short* __restrict__ PTb, short* __restrict__ GTb) {
    int e = blockIdx.x * 256 + threadIdx.x;
    if (e < 589824) {   // TQ (conv seg0, KS=2, P only)
        TQb[e] = f2b(PPART[e] + PPART[e + 589824]);
        return;
    }
    int e2 = e - 589824;
    const int EC[5]  = {0, 589824, 737280, 786432, 802816};
    const int KSv[4] = {2, 4, 8, 16};
    const int NPv[4] = {589824, 147456, 49152, 16384};
    const int PBv[4] = {1179648, 2359296, 2949120, 3342336};
    const int GBv[4] = {0, 1179648, 1769472, 2162688};
    const int POv[4] = {589824, 1179648, 1327104, 1376256};
    int sg = (e2 < EC[1]) ? 0 : (e2 < EC[2]) ? 1 : (e2 < EC[3]) ? 2 : 3;
    int rem = e2 - EC[sg];
    int KS = KSv[sg], NP = NPv[sg];
    const float* ps = PPART + PBv[sg] + rem;
    const float* gs = GPART + GBv[sg] + rem;
    float p = 0.f, g = 0.f;
    for (int s = 0; s < KS; ++s) {
        p += ps[(size_t)s * NP];
        g += gs[(size_t)s * NP];
    }
    PTb[POv[sg] + rem] = f2b(p);
    GTb[POv[sg] + rem] = f2b(g);
}

// ---------------- K2: MFMA attention — async-LDS-staged chunks ----------------
// grid = 2*4*72 + 3*72 = 792. Segs 0/1 write f32 partials (PNUM/PL), combined
// inside k_z; segs 2-4 write OUTb.
__global__ __launch_bounds__(256) void k_attn(const short* __restrict__ tq,
                                              const short* __restrict__ PTb,
                                              const short* __restrict__ GTb,
                                              short* __restrict__ OUTb,
                                              float* __restrict__ PNUM,
                                              float* __restrict__ PL) {
    const int AM[5]    = {2304, 2304, 576, 144, 36};
    const int AMp[5]   = {2304, 2304, 576, 192, 64};
    const int APOFF[5] = {0, 589824, 1179648, 1327104, 1376256};

    __shared__ __align__(16) short s_tile[2][8192];   // [buf][PT 4096 | GT 4096]
    __shared__ __align__(16) short s_P[4][32][72];

    int t = threadIdx.x;
    int bid = blockIdx.x;
    int seg, r, p;
    if (bid < 576) { seg = bid / 288; int wi = bid % 288; p = wi / 72; r = wi % 72; }
    else           { int q = bid - 576; seg = 2 + q / 72; r = q % 72; p = 0; }
    int b = r / 18;
    int n0 = (r % 18) * 128;
    int M = AM[seg], Mp = AMp[seg];
    const short* pT = PTb + APOFF[seg];
    const short* gT = GTb + APOFF[seg];

    int w = t >> 6, lane = t & 63, lo = lane & 15, quad = lane >> 4;
    bool domask = (M != Mp);   // segs 3/4 only
    bool split = (seg < 2);
    int n0w = n0 + w * 32;

    int c0, c1;
    if (split) { c0 = p * 9; c1 = c0 + 9; }
    else       { c0 = 0; c1 = Mp >> 6; }

    // Q fragments (B-operand): rows n0w + i*16 + lo, k = c(64)
    const short* tqB = tq + ((size_t)b * NN + n0w + lo) * 64 + quad * 8;
    bf16x8 bq[2][2];
#pragma unroll
    for (int i = 0; i < 2; ++i)
#pragma unroll
        for (int h = 0; h < 2; ++h)
            bq[i][h] = *(const bf16x8*)(tqB + i * 16 * 64 + h * 32);

    const short* ptSeg = pT + (size_t)b * Mp * 64;   // [m][64c] rows
    const short* gtSeg = gT + (size_t)b * 64 * Mp;   // [64c][m] rows

    f32x4 accO[2][4];
#pragma unroll
    for (int i = 0; i < 2; ++i)
#pragma unroll
        for (int cs = 0; cs < 4; ++cs)
            accO[i][cs] = f32x4{0.f, 0.f, 0.f, 0.f};
    float lsum[2] = {0.f, 0.f};

    short (*sp)[72] = s_P[w];   // wave-private P' tile [32 n][64 m, pad 72]

#define STAGE(BUF, M0)                                                          \
    {                                                                           \
        _Pragma("unroll")                                                       \
        for (int j = 0; j < 2; ++j) {                                           \
            int slab = w * 2 + j;                                               \
            int Bb = slab * 1024 + lane * 16;                                   \
            int srcb = Bb ^ (((Bb >> 7) & 7) << 4);                             \
            gl2lds16((const char*)(ptSeg + (size_t)(M0) * 64) + srcb,           \
                     &s_tile[BUF][slab * 512]);                                 \
        }                                                                       \
        _Pragma("unroll")                                                       \
        for (int j = 0; j < 2; ++j) {                                           \
            int slab = w * 2 + j;                                               \
            int row = slab * 8 + (lane >> 3);                                   \
            int colb = (lane & 7) * 16;                                         \
            int colbs = colb ^ ((row & 7) << 4);                                \
            gl2lds16((const char*)(gtSeg + (size_t)row * Mp + (M0)) + colbs,    \
                     &s_tile[BUF][4096 + slab * 512]);                          \
        }                                                                       \
    }

    int buf = 0;
    STAGE(0, c0 << 6);
    __syncthreads();

    int swz = (lo & 7) << 4;
    for (int ch = c0; ch < c1; ++ch) {
        int m0 = ch << 6;
        bool more = (ch + 1 < c1);
        if (more) STAGE(buf ^ 1, m0 + 64);

        const char* ptL = (const char*)&s_tile[buf][0];
        const char* gtL = (const char*)&s_tile[buf][4096];
        bf16x8 pa[4][2], gb[4][2];
#pragma unroll
        for (int ms = 0; ms < 4; ++ms)
#pragma unroll
            for (int h = 0; h < 2; ++h) {
                int A = (ms * 16 + lo) * 128 + h * 64 + quad * 16;
                pa[ms][h] = *(const bf16x8*)(ptL + (A ^ swz));
                gb[ms][h] = *(const bf16x8*)(gtL + (A ^ swz));
            }

        // QK: S[i][ms] -> lane holds (m = m0+ms*16+quad*4+rg, n = n0w+i*16+lo)
        f32x4 S[2][4];
#pragma unroll
        for (int i = 0; i < 2; ++i)
#pragma unroll
            for (int ms = 0; ms < 4; ++ms) {
                S[i][ms] = f32x4{0.f, 0.f, 0.f, 0.f};
                S[i][ms] = __builtin_amdgcn_mfma_f32_16x16x32_bf16(pa[ms][0], bq[i][0], S[i][ms], 0, 0, 0);
                S[i][ms] = __builtin_amdgcn_mfma_f32_16x16x32_bf16(pa[ms][1], bq[i][1], S[i][ms], 0, 0, 0);
            }
        if (domask) {
#pragma unroll
            for (int ms = 0; ms < 4; ++ms)
#pragma unroll
                for (int rg = 0; rg < 4; ++rg) {
                    bool oob = (m0 + ms * 16 + quad * 4 + rg) >= M;
                    if (oob) { S[0][ms][rg] = -1e30f; S[1][ms][rg] = -1e30f; }
                }
        }
        // exp(s-40), accumulate l, write P' [n][m] to wave-private LDS
#pragma unroll
        for (int i = 0; i < 2; ++i)
#pragma unroll
            for (int ms = 0; ms < 4; ++ms) {
                short4 pw;
#pragma unroll
                for (int rg = 0; rg < 4; ++rg) {
                    float e = __expf(S[i][ms][rg] - 40.f);
                    lsum[i] += e;
                    ((short*)&pw)[rg] = f2b(e);
                }
                *(short4*)&sp[i * 16 + lo][ms * 16 + quad * 4] = pw;
            }
        // read back as A-operand: rows n (i*16+lo), k = m (in-wave lgkm only)
        bf16x8 pf[2][2];
#pragma unroll
        for (int i = 0; i < 2; ++i)
#pragma unroll
            for (int h = 0; h < 2; ++h)
                pf[i][h] = *(const bf16x8*)&sp[i * 16 + lo][h * 32 + quad * 8];
        // AV: accO[i][cs] -> lane holds (n = n0w+i*16+quad*4+rg, c = cs*16+lo)
#pragma unroll
        for (int i = 0; i < 2; ++i)
#pragma unroll
            for (int cs = 0; cs < 4; ++cs) {
                accO[i][cs] = __builtin_amdgcn_mfma_f32_16x16x32_bf16(pf[i][0], gb[cs][0], accO[i][cs], 0, 0, 0);
                accO[i][cs] = __builtin_amdgcn_mfma_f32_16x16x32_bf16(pf[i][1], gb[cs][1], accO[i][cs], 0, 0, 0);
            }
        __syncthreads();   // stage(ch+1) complete + buffer reuse safe
        buf ^= 1;
    }
#undef STAGE
    // l: full in-wave reduction (lane j holds l[n = i*16 + (j&15)])
#pragma unroll
    for (int i = 0; i < 2; ++i) {
        lsum[i] += __shfl_xor(lsum[i], 16, 64);
        lsum[i] += __shfl_xor(lsum[i], 32, 64);
    }
    if (split) {
        float* np = PNUM + ((size_t)((seg * 4 + p) * 72 + r)) * 8192;
        float* lp = PL + ((size_t)((seg * 4 + p) * 72 + r)) * 128;
        if (quad == 0) {
            lp[w * 32 + lo] = lsum[0];
            lp[w * 32 + 16 + lo] = lsum[1];
        }
#pragma unroll
        for (int i = 0; i < 2; ++i)
#pragma unroll
            for (int cs = 0; cs < 4; ++cs)
#pragma unroll
                for (int rg = 0; rg < 4; ++rg) {
                    int nl = w * 32 + i * 16 + quad * 4 + rg;
                    np[nl * 64 + cs * 16 + lo] = accO[i][cs][rg];
                }
    } else {
        short* outm = OUTb + (size_t)seg * 589824;
#pragma unroll
        for (int i = 0; i < 2; ++i)
#pragma unroll
            for (int rg = 0; rg < 4; ++rg) {
                float lt = __shfl(lsum[i], quad * 4 + rg, 64);
                int n = n0w + i * 16 + quad * 4 + rg;
#pragma unroll
                for (int cs = 0; cs < 4; ++cs)
                    outm[((size_t)b * NN + n) * 64 + cs * 16 + lo] = f2b(accO[i][cs][rg] / lt);
            }
    }
}

// ---------------- K3: MFMA z-conv + BN partial stats, FUSED attn-combine ------
__global__ __launch_bounds__(256) void k_z(const short* __restrict__ OUTb,
                                           const float* __restrict__ z_w,
                                           const float* __restrict__ PNUM,
                                           const float* __restrict__ PL,
                                           short* __restrict__ Zb,
                                           float* __restrict__ PART) {
    __shared__ __align__(16) short s_ut[64][72];
    int t = threadIdx.x;
    int seg = blockIdx.x / 144;
    int r = blockIdx.x % 144;
    int b = r / 36;
    int sp0 = (r % 36) * 64;
    short* z = Zb + (size_t)seg * 2359296 + (size_t)b * 589824;
    float* part = PART + (size_t)(seg * 144 + r) * 512;

    int w = t >> 6, lane = t & 63, lo = lane & 15, quad = lane >> 4;

    bf16x8 af[4][2];
#pragma unroll
    for (int qt = 0; qt < 4; ++qt)
#pragma unroll
        for (int h = 0; h < 2; ++h)
            af[qt][h] = ld8cvt(&z_w[(size_t)(w * 64 + qt * 16 + lo) * 64 + h * 32 + quad * 8]);

    if (seg < 2) {
        int sp036 = r % 36;
#pragma unroll
        for (int rr = 0; rr < 4; ++rr) {
            int idx = t + rr * 256;
            int spl = idx & 63;
            int cp0 = (idx >> 6) << 2;
            short4 pk;
#pragma unroll
            for (int j = 0; j < 4; ++j) {
                int ng = (cp0 + j) * 36 + sp036;
                int rb = b * 18 + (ng >> 7);
                int nl = ng & 127;
                float num = 0.f, l = 0.f;
#pragma unroll
                for (int pp = 0; pp < 4; ++pp) {
                    size_t base = (size_t)((seg * 4 + pp) * 72 + rb);
                    num += PNUM[base * 8192 + nl * 64 + spl];
                    l   += PL[base * 128 + nl];
                }
                ((short*)&pk)[j] = f2b(num / l);
            }
            *(short4*)&s_ut[spl][cp0] = pk;
        }
    } else {
        const short* F = OUTb + (size_t)seg * 589824 + (size_t)b * 147456;
#pragma unroll
        for (int rr = 0; rr < 4; ++rr) {
            int idx = t + rr * 256;
            int spl = idx & 63;
            int cp0 = (idx >> 6) << 2;
            short4 pk;
            pk.x = F[(size_t)(cp0 + 0) * 2304 + sp0 + spl];
            pk.y = F[(size_t)(cp0 + 1) * 2304 + sp0 + spl];
            pk.z = F[(size_t)(cp0 + 2) * 2304 + sp0 + spl];
            pk.w = F[(size_t)(cp0 + 3) * 2304 + sp0 + spl];
            *(short4*)&s_ut[spl][cp0] = pk;
        }
    }
    __syncthreads();

    bf16x8 bfr[4][2];
#pragma unroll
    for (int st = 0; st < 4; ++st)
#pragma unroll
        for (int h = 0; h < 2; ++h)
            bfr[st][h] = *(const bf16x8*)&s_ut[st * 16 + lo][h * 32 + quad * 8];

    f32x4 acc[4][4];
#pragma unroll
    for (int qt = 0; qt < 4; ++qt)
#pragma unroll
        for (int st = 0; st < 4; ++st) {
            acc[qt][st] = f32x4{0.f, 0.f, 0.f, 0.f};
            acc[qt][st] = __builtin_amdgcn_mfma_f32_16x16x32_bf16(af[qt][0], bfr[st][0], acc[qt][st], 0, 0, 0);
            acc[qt][st] = __builtin_amdgcn_mfma_f32_16x16x32_bf16(af[qt][1], bfr[st][1], acc[qt][st], 0, 0, 0);
        }

#pragma unroll
    for (int qt = 0; qt < 4; ++qt) {
        float s1[4] = {0.f, 0.f, 0.f, 0.f};
        float s2[4] = {0.f, 0.f, 0.f, 0.f};
        int qb = w * 64 + qt * 16 + quad * 4;
#pragma unroll
        for (int st = 0; st < 4; ++st) {
            int sp = sp0 + st * 16 + lo;
#pragma unroll
            for (int rg = 0; rg < 4; ++rg) {
                float v = acc[qt][st][rg];
                z[(size_t)(qb + rg) * 2304 + sp] = f2b(v);
                s1[rg] += v;
                s2[rg] += v * v;
            }
        }
#pragma unroll
        for (int rg = 0; rg < 4; ++rg) {
            for (int o = 8; o >= 1; o >>= 1) {
                s1[rg] += __shfl_xor(s1[rg], o, 16);
                s2[rg] += __shfl_xor(s2[rg], o, 16);
            }
            if (lo == 0) {
                float2 v2; v2.x = s1[rg]; v2.y = s2[rg];
                *(float2*)&part[(size_t)(qb + rg) * 2] = v2;
            }
        }
    }
}

// ---------------- K3b: reduce per-block BN partials -> STATS ----------------
__global__ __launch_bounds__(256) void k_stats(const float* __restrict__ PART,
                                               float* __restrict__ STATS) {
    int seg = blockIdx.x;
    int q = threadIdx.x;
    const float* p = PART + (size_t)seg * 144 * 512 + q * 2;
    float s1 = 0.f, s2 = 0.f;
#pragma unroll 16
    for (int blk = 0; blk < 144; ++blk) {
        float2 v = *(const float2*)&p[(size_t)blk * 512];
        s1 += v.x; s2 += v.y;
    }
    STATS[seg * 512 + q * 2] = s1;
    STATS[seg * 512 + q * 2 + 1] = s2;
}

// ---------------- K4: final BN-normalize-and-sum, vectorized x4 ----------------
__global__ __launch_bounds__(256) void k_final(
    const short* __restrict__ Zb, const float* __restrict__ STATS,
    const float* g0, const float* g1, const float* g2, const float* g3, const float* g4,
    const float* b0, const float* b1, const float* b2, const float* b3, const float* b4,
    float* __restrict__ outp) {
    int idx4 = (blockIdx.x * 256 + threadIdx.x) * 4;
    int q = (idx4 / NN) & 255;
    const float inv = 1.f / (float)(BB * NN);
    float4 o = {0.f, 0.f, 0.f, 0.f};
#pragma unroll
    for (int i = 0; i < 5; ++i) {
        float mean = STATS[i * 512 + q * 2] * inv;
        float var = STATS[i * 512 + q * 2 + 1] * inv - mean * mean;
        float rr = rsqrtf(var + 1e-5f);
        const float* gm = (i == 0) ? g0 : (i == 1) ? g1 : (i == 2) ? g2 : (i == 3) ? g3 : g4;
        const float* bt = (i == 0) ? b0 : (i == 1) ? b1 : (i == 2) ? b2 : (i == 3) ? b3 : b4;
        float sc = rr * gm[q];
        float ofs = bt[q] - mean * sc;
        short4 zv = *(const short4*)&Zb[(size_t)i * 2359296 + idx4];
        o.x += b2f16(zv.x) * sc + ofs;
        o.y += b2f16(zv.y) * sc + ofs;
        o.z += b2f16(zv.z) * sc + ofs;
        o.w += b2f16(zv.w) * sc + ofs;
    }
    *(float4*)&outp[idx4] = o;
}

extern "C" void kernel_launch(void* const* d_in, const int* in_sizes, int n_in,
                              void* d_out, int out_size, void* d_ws, size_t ws_size,
                              hipStream_t stream) {
    const float* persp = (const float*)d_in[0];
    const float* resp[5];
    for (int i = 0; i < 5; ++i) resp[i] = (const float*)d_in[1 + i];
    const float* t_w = (const float*)d_in[6];
    const float* z_w = (const float*)d_in[7];
    const float *p_w[5], *g_w[5], *bng[5], *bnb[5];
    for (int i = 0; i < 5; ++i) {
        p_w[i] = (const float*)d_in[8 + 4 * i];
        g_w[i] = (const float*)d_in[9 + 4 * i];
        bng[i] = (const float*)d_in[10 + 4 * i];
        bnb[i] = (const float*)d_in[11 + 4 * i];
    }
    // workspace layout (~81 MB total)
    short* TQb  = (short*)d_ws;             // 589,824
    short* TWb  = TQb + 589824;             // 16,384
    short* WPb  = TWb + 16384;              // 249,856
    short* WGb  = WPb + 249856;             // 249,856
    short* PTb  = WGb + 249856;             // 1,392,640
    short* GTb  = PTb + 1392640;            // 1,392,640
    short* Zb   = GTb + 1392640;            // 11,796,480
    short* OUTb = Zb + 11796480;            // 2,949,120  (only segs 2-4 used)
    float* STATS = (float*)(OUTb + 2949120);  // 2,560
    float* PPART = STATS + 2560;            // 3,604,480 (TQ + split-K partials; reused as BN partials by k_z)
    float* GPART = PPART + 3604480;         // 2,424,832
    float* PNUM  = GPART + 2424832;         // 4,718,592 (attn split-m numerators)
    float* PL    = PNUM + 4718592;          // 73,728    (attn split-m denominators)

    k_wcvt<<<2016, 256, 0, stream>>>(t_w,
        p_w[0], p_w[1], p_w[2], p_w[3], p_w[4],
        g_w[0], g_w[1], g_w[2], g_w[3], g_w[4],
        TWb, WPb, WGb);
    k_conv<<<1024, 256, 0, stream>>>(persp,
        resp[0], resp[1], resp[2], resp[3], resp[4],
        TWb, WPb, WGb, PTb, GTb, PPART, GPART);
    k_cvt<<<5440, 256, 0, stream>>>(PPART, GPART, TQb, PTb, GTb);
    k_attn<<<792, 256, 0, stream>>>(TQb, PTb, GTb, OUTb, PNUM, PL);
    k_z<<<720, 256, 0, stream>>>(OUTb, z_w, PNUM, PL, Zb, PPART);
    k_stats<<<5, 256, 0, stream>>>(PPART, STATS);
    k_final<<<2304, 256, 0, stream>>>(Zb, STATS,
        bng[0], bng[1], bng[2], bng[3], bng[4],
        bnb[0], bnb[1], bnb[2], bnb[3], bnb[4],
        (float*)d_out);
}

// Round 11
// 216.733 us; speedup vs baseline: 1.0133x; 1.0133x over previous
//
#include <hip/hip_runtime.h>
#include <hip/hip_bf16.h>
#include <string.h>

#define BB 4
#define CPc 256
#define NN 2304   // 48*48

typedef __attribute__((ext_vector_type(8))) short bf16x8;
typedef __attribute__((ext_vector_type(4))) float f32x4;

__device__ __forceinline__ short f2b(float x) {
    __hip_bfloat16 h = __float2bfloat16(x);
    return *reinterpret_cast<short*>(&h);
}
__device__ __forceinline__ float b2f16(short v) {
    union { float f; unsigned u; } x;
    x.u = ((unsigned)(unsigned short)v) << 16;
    return x.f;
}

// load 8 consecutive f32, convert to a bf16x8 fragment (RNE)
__device__ __forceinline__ bf16x8 ld8cvt(const float* p) {
    const float4 a = *(const float4*)p;
    const float4 b = *(const float4*)(p + 4);
    bf16x8 r;
    r[0] = f2b(a.x); r[1] = f2b(a.y); r[2] = f2b(a.z); r[3] = f2b(a.w);
    r[4] = f2b(b.x); r[5] = f2b(b.y); r[6] = f2b(b.z); r[7] = f2b(b.w);
    return r;
}

// async global->LDS DMA, 16B per lane, dest = uniform base + lane*16
__device__ __forceinline__ void gl2lds16(const void* g, void* l) {
    __builtin_amdgcn_global_load_lds(
        (const __attribute__((address_space(1))) void*)g,
        (__attribute__((address_space(3))) void*)l, 16, 0, 0);
}

// ---------------- K0: convert CONV weights fp32 -> bf16 ----------------------
// grid = (16384 + 2*249856)/256 = 2016
__global__ __launch_bounds__(256) void k_wcvt(
    const float* __restrict__ t_w,
    const float* p0, const float* p1, const float* p2, const float* p3, const float* p4,
    const float* g0, const float* g1, const float* g2, const float* g3, const float* g4,
    short* __restrict__ TWb, short* __restrict__ WPb, short* __restrict__ WGb) {
    int idx = blockIdx.x * 256 + threadIdx.x;
    if (idx < 16384) { TWb[idx] = f2b(t_w[idx]); return; }
    int k = idx - 16384;
    bool isP = k < 249856;
    if (!isP) k -= 249856;
    int i, off;
    if (k < 4096)        { i = 0; off = 0; }
    else if (k < 20480)  { i = 1; off = 4096; }
    else if (k < 53248)  { i = 2; off = 20480; }
    else if (k < 118784) { i = 3; off = 53248; }
    else                 { i = 4; off = 118784; }
    const float* s;
    if (isP) s = (i == 0) ? p0 : (i == 1) ? p1 : (i == 2) ? p2 : (i == 3) ? p3 : p4;
    else     s = (i == 0) ? g0 : (i == 1) ? g1 : (i == 2) ? g2 : (i == 3) ? g3 : g4;
    (isP ? WPb : WGb)[k] = f2b(s[k - off]);
}

// ---------------- K1: batched MFMA 1x1 convs — single-barrier double-buffered
// (R8-verified structure) -----------------------------------------------------
__global__ __launch_bounds__(256) void k_conv(
    const float* __restrict__ persp,
    const float* r0, const float* r1, const float* r2, const float* r3, const float* r4,
    const short* __restrict__ TWb, const short* __restrict__ WPb, const short* __restrict__ WGb,
    short* __restrict__ TQb, short* __restrict__ PTb, short* __restrict__ GTb,
    float* __restrict__ PPART, float* __restrict__ GPART) {
    const int CUM[7]  = {0, 144, 288, 432, 504, 552, 584};
    const int CRs[6]  = {256, 64, 256, 512, 1024, 2048};
    const int Mus[6]  = {2304, 2304, 2304, 576, 144, 36};
    const int Mps[6]  = {2304, 2304, 2304, 576, 192, 64};
    const int KSs[6]  = {1, 1, 1, 2, 4, 8};
    const int WOFF[6] = {0, 0, 4096, 20480, 53248, 118784};
    const int POFF[6] = {0, 0, 589824, 1179648, 1327104, 1376256};
    const int PBASE[6] = {0, 0, 0, 0, 294912, 491520};

    __shared__ __align__(16) short s_a[2][64][72];

    int blk = blockIdx.x, t = threadIdx.x;
    int w = t >> 6, lane = t & 63, lo = lane & 15, quad = lane >> 4;
    int seg = 0;
#pragma unroll
    for (int s_ = 1; s_ <= 5; ++s_) if (blk >= CUM[s_]) seg = s_;
    int Cr = CRs[seg], M = Mus[seg], Mp = Mps[seg], KS = KSs[seg];
    const float* in = (seg == 0) ? persp : (seg == 1) ? r0 : (seg == 2) ? r1 :
                      (seg == 3) ? r2 : (seg == 4) ? r3 : r4;
    const short* wp = (seg == 0) ? TWb : WPb + WOFF[seg];
    const short* wg = WGb + WOFF[seg];
    bool has_g = (seg != 0);
    int local = blk - CUM[seg];
    int mt = Mp >> 6;
    int b = local / (mt * KS);
    int rem = local % (mt * KS);
    int m0 = (rem / KS) * 64;
    int ksi = rem % KS;
    int kLen = Cr / KS, k0 = ksi * kLen;

    int ml = t & 63;
    int ssw = (ml >> 3) & 7;
    bool mvalid = (m0 + ml) < M;
    const float* inB = in + ((size_t)b * Cr) * M + m0 + ml;

    int mrow = w * 16 + lo;
    int rsw = (mrow >> 3) & 7;

    f32x4 accP[4], accG[4];
#pragma unroll
    for (int ct = 0; ct < 4; ++ct) {
        accP[ct] = f32x4{0.f, 0.f, 0.f, 0.f};
        accG[ct] = f32x4{0.f, 0.f, 0.f, 0.f};
    }

    float pv0[8], pv1[8];
#define LOADCH(KC)                                                              \
    {                                                                           \
        _Pragma("unroll")                                                       \
        for (int r = 0; r < 8; ++r) {                                           \
            int kp = w + r * 4;                                                 \
            pv0[r] = 0.f; pv1[r] = 0.f;                                         \
            if (mvalid) {                                                       \
                pv0[r] = inB[(size_t)((KC) + 2 * kp) * M];                      \
                pv1[r] = inB[(size_t)((KC) + 2 * kp + 1) * M];                  \
            }                                                                   \
        }                                                                       \
    }
#define WRITECH(BUF)                                                            \
    {                                                                           \
        _Pragma("unroll")                                                       \
        for (int r = 0; r < 8; ++r) {                                           \
            int kp = w + r * 4;                                                 \
            int q = kp >> 2, l = kp & 3;                                        \
            short2 pk; pk.x = f2b(pv0[r]); pk.y = f2b(pv1[r]);                  \
            *(short2*)&s_a[BUF][ml][(q ^ ssw) * 8 + l * 2] = pk;                \
        }                                                                       \
    }

    // prologue: stage chunk 0
    LOADCH(k0);
    WRITECH(0);
    __syncthreads();

    int cur = 0;
    for (int kc = k0; kc < k0 + kLen; kc += 64) {
        bool more = (kc + 64) < (k0 + kLen);
        if (more) LOADCH(kc + 64);   // issue next chunk's inputs early

        // weight fragments for this chunk (bf16, L2-hot; overlap with ds_reads)
        bf16x8 wf0[4], wf1[4], wg0[4], wg1[4];
#pragma unroll
        for (int ct = 0; ct < 4; ++ct) {
            wf0[ct] = *(const bf16x8*)&wp[(size_t)(ct * 16 + lo) * Cr + kc + quad * 8];
            wf1[ct] = *(const bf16x8*)&wp[(size_t)(ct * 16 + lo) * Cr + kc + 32 + quad * 8];
            if (has_g) {
                wg0[ct] = *(const bf16x8*)&wg[(size_t)(ct * 16 + lo) * Cr + kc + quad * 8];
                wg1[ct] = *(const bf16x8*)&wg[(size_t)(ct * 16 + lo) * Cr + kc + 32 + quad * 8];
            }
        }
        const bf16x8 fr0 = *(const bf16x8*)&s_a[cur][mrow][8 * (quad ^ rsw)];
        const bf16x8 fr1 = *(const bf16x8*)&s_a[cur][mrow][8 * ((4 + quad) ^ rsw)];
#pragma unroll
        for (int ct = 0; ct < 4; ++ct) {
            accP[ct] = __builtin_amdgcn_mfma_f32_16x16x32_bf16(fr0, wf0[ct], accP[ct], 0, 0, 0);
            accP[ct] = __builtin_amdgcn_mfma_f32_16x16x32_bf16(fr1, wf1[ct], accP[ct], 0, 0, 0);
            if (has_g) {
                accG[ct] = __builtin_amdgcn_mfma_f32_16x16x32_bf16(wg0[ct], fr0, accG[ct], 0, 0, 0);
                accG[ct] = __builtin_amdgcn_mfma_f32_16x16x32_bf16(wg1[ct], fr1, accG[ct], 0, 0, 0);
            }
        }
        if (more) WRITECH(cur ^ 1);  // vmcnt wait lands here, after MFMA
        __syncthreads();             // one barrier per chunk
        cur ^= 1;
    }
#undef LOADCH
#undef WRITECH

    if (KS == 1) {
        short* outP = (seg == 0) ? TQb : PTb + POFF[seg];
        short* outG = GTb + POFF[seg];
        int mP = m0 + w * 16 + quad * 4;
#pragma unroll
        for (int ct = 0; ct < 4; ++ct) {
            int c = ct * 16 + lo;
#pragma unroll
            for (int rg = 0; rg < 4; ++rg)
                outP[((size_t)b * Mp + mP + rg) * 64 + c] = f2b(accP[ct][rg]);
        }
        if (has_g) {
            int mG = m0 + w * 16 + lo;
#pragma unroll
            for (int ct = 0; ct < 4; ++ct) {
                int cG = ct * 16 + quad * 4;
#pragma unroll
                for (int rg = 0; rg < 4; ++rg)
                    outG[((size_t)b * 64 + cG + rg) * Mp + mG] = f2b(accG[ct][rg]);
            }
        }
    } else {
        int NP = 4 * Mp * 64;
        float* pp = PPART + PBASE[seg] + (size_t)ksi * NP;
        float* gp = GPART + PBASE[seg] + (size_t)ksi * NP;
        int mP = m0 + w * 16 + quad * 4;
#pragma unroll
        for (int ct = 0; ct < 4; ++ct) {
            int c = ct * 16 + lo;
#pragma unroll
            for (int rg = 0; rg < 4; ++rg)
                pp[((size_t)b * Mp + mP + rg) * 64 + c] = accP[ct][rg];
        }
        int mG = m0 + w * 16 + lo;
#pragma unroll
        for (int ct = 0; ct < 4; ++ct) {
            int cG = ct * 16 + quad * 4;
#pragma unroll
            for (int rg = 0; rg < 4; ++rg)
                gp[((size_t)b * 64 + cG + rg) * Mp + mG] = accG[ct][rg];
        }
    }
}

// ---------------- K1b: reduce split-K partials -> bf16 PTb/GTb ----------------
__global__ __launch_bounds__(256) void k_cvt(const float* __restrict__ PPART,
                                             const float* __restrict__ GPART,
                                             short* __restrict__ PTb, short* __restrict__ GTb) {
    const int EC[4]    = {0, 147456, 196608, 212992};
    const int KSv[3]   = {2, 4, 8};
    const int PBASEv[3] = {0, 294912, 491520};
    const int POFFv[3] = {1179648, 1327104, 1376256};
    int e = blockIdx.x * 256 + threadIdx.x;
    int sg = (e < EC[1]) ? 0 : (e < EC[2]) ? 1 : 2;
    int rem = e - EC[sg];
    int KS = KSv[sg];
    int NP = (sg == 0) ? 147456 : (sg == 1) ? 49152 : 16384;
    {
        const float* src = PPART + PBASEv[sg] + rem;
        float p = 0.f;
        for (int s = 0; s < KS; ++s) p += src[(size_t)s * NP];
        PTb[POFFv[sg] + rem] = f2b(p);
    }
    {
        const float* src = GPART + PBASEv[sg] + rem;
        float g = 0.f;
        for (int s = 0; s < KS; ++s) g += src[(size_t)s * NP];
        GTb[POFFv[sg] + rem] = f2b(g);
    }
}

// ---------------- K2: MFMA attention — async-LDS-staged chunks ----------------
// grid = 2*4*72 + 3*72 = 792. Segs 0/1 write f32 partials (PNUM/PL), combined
// inside k_z; segs 2-4 write OUTb.
__global__ __launch_bounds__(256) void k_attn(const short* __restrict__ tq,
                                              const short* __restrict__ PTb,
                                              const short* __restrict__ GTb,
                                              short* __restrict__ OUTb,
                                              float* __restrict__ PNUM,
                                              float* __restrict__ PL) {
    const int AM[5]    = {2304, 2304, 576, 144, 36};
    const int AMp[5]   = {2304, 2304, 576, 192, 64};
    const int APOFF[5] = {0, 589824, 1179648, 1327104, 1376256};

    __shared__ __align__(16) short s_tile[2][8192];   // [buf][PT 4096 | GT 4096]
    __shared__ __align__(16) short s_P[4][32][72];

    int t = threadIdx.x;
    int bid = blockIdx.x;
    int seg, r, p;
    if (bid < 576) { seg = bid / 288; int wi = bid % 288; p = wi / 72; r = wi % 72; }
    else           { int q = bid - 576; seg = 2 + q / 72; r = q % 72; p = 0; }
    int b = r / 18;
    int n0 = (r % 18) * 128;
    int M = AM[seg], Mp = AMp[seg];
    const short* pT = PTb + APOFF[seg];
    const short* gT = GTb + APOFF[seg];

    int w = t >> 6, lane = t & 63, lo = lane & 15, quad = lane >> 4;
    bool domask = (M != Mp);   // segs 3/4 only
    bool split = (seg < 2);
    int n0w = n0 + w * 32;

    int c0, c1;
    if (split) { c0 = p * 9; c1 = c0 + 9; }
    else       { c0 = 0; c1 = Mp >> 6; }

    // Q fragments (B-operand): rows n0w + i*16 + lo, k = c(64)
    const short* tqB = tq + ((size_t)b * NN + n0w + lo) * 64 + quad * 8;
    bf16x8 bq[2][2];
#pragma unroll
    for (int i = 0; i < 2; ++i)
#pragma unroll
        for (int h = 0; h < 2; ++h)
            bq[i][h] = *(const bf16x8*)(tqB + i * 16 * 64 + h * 32);

    const short* ptSeg = pT + (size_t)b * Mp * 64;   // [m][64c] rows
    const short* gtSeg = gT + (size_t)b * 64 * Mp;   // [64c][m] rows

    f32x4 accO[2][4];
#pragma unroll
    for (int i = 0; i < 2; ++i)
#pragma unroll
        for (int cs = 0; cs < 4; ++cs)
            accO[i][cs] = f32x4{0.f, 0.f, 0.f, 0.f};
    float lsum[2] = {0.f, 0.f};

    short (*sp)[72] = s_P[w];   // wave-private P' tile [32 n][64 m, pad 72]

#define STAGE(BUF, M0)                                                          \
    {                                                                           \
        _Pragma("unroll")                                                       \
        for (int j = 0; j < 2; ++j) {                                           \
            int slab = w * 2 + j;                                               \
            int Bb = slab * 1024 + lane * 16;                                   \
            int srcb = Bb ^ (((Bb >> 7) & 7) << 4);                             \
            gl2lds16((const char*)(ptSeg + (size_t)(M0) * 64) + srcb,           \
                     &s_tile[BUF][slab * 512]);                                 \
        }                                                                       \
        _Pragma("unroll")                                                       \
        for (int j = 0; j < 2; ++j) {                                           \
            int slab = w * 2 + j;                                               \
            int row = slab * 8 + (lane >> 3);                                   \
            int colb = (lane & 7) * 16;                                         \
            int colbs = colb ^ ((row & 7) << 4);                                \
            gl2lds16((const char*)(gtSeg + (size_t)row * Mp + (M0)) + colbs,    \
                     &s_tile[BUF][4096 + slab * 512]);                          \
        }                                                                       \
    }

    int buf = 0;
    STAGE(0, c0 << 6);
    __syncthreads();

    int swz = (lo & 7) << 4;
    for (int ch = c0; ch < c1; ++ch) {
        int m0 = ch << 6;
        bool more = (ch + 1 < c1);
        if (more) STAGE(buf ^ 1, m0 + 64);

        const char* ptL = (const char*)&s_tile[buf][0];
        const char* gtL = (const char*)&s_tile[buf][4096];
        bf16x8 pa[4][2], gb[4][2];
#pragma unroll
        for (int ms = 0; ms < 4; ++ms)
#pragma unroll
            for (int h = 0; h < 2; ++h) {
                int A = (ms * 16 + lo) * 128 + h * 64 + quad * 16;
                pa[ms][h] = *(const bf16x8*)(ptL + (A ^ swz));
                gb[ms][h] = *(const bf16x8*)(gtL + (A ^ swz));
            }

        // QK: S[i][ms] -> lane holds (m = m0+ms*16+quad*4+rg, n = n0w+i*16+lo)
        f32x4 S[2][4];
#pragma unroll
        for (int i = 0; i < 2; ++i)
#pragma unroll
            for (int ms = 0; ms < 4; ++ms) {
                S[i][ms] = f32x4{0.f, 0.f, 0.f, 0.f};
                S[i][ms] = __builtin_amdgcn_mfma_f32_16x16x32_bf16(pa[ms][0], bq[i][0], S[i][ms], 0, 0, 0);
                S[i][ms] = __builtin_amdgcn_mfma_f32_16x16x32_bf16(pa[ms][1], bq[i][1], S[i][ms], 0, 0, 0);
            }
        if (domask) {
#pragma unroll
            for (int ms = 0; ms < 4; ++ms)
#pragma unroll
                for (int rg = 0; rg < 4; ++rg) {
                    bool oob = (m0 + ms * 16 + quad * 4 + rg) >= M;
                    if (oob) { S[0][ms][rg] = -1e30f; S[1][ms][rg] = -1e30f; }
                }
        }
        // exp(s-40), accumulate l, write P' [n][m] to wave-private LDS
#pragma unroll
        for (int i = 0; i < 2; ++i)
#pragma unroll
            for (int ms = 0; ms < 4; ++ms) {
                short4 pw;
#pragma unroll
                for (int rg = 0; rg < 4; ++rg) {
                    float e = __expf(S[i][ms][rg] - 40.f);
                    lsum[i] += e;
                    ((short*)&pw)[rg] = f2b(e);
                }
                *(short4*)&sp[i * 16 + lo][ms * 16 + quad * 4] = pw;
            }
        // read back as A-operand: rows n (i*16+lo), k = m (in-wave lgkm only)
        bf16x8 pf[2][2];
#pragma unroll
        for (int i = 0; i < 2; ++i)
#pragma unroll
            for (int h = 0; h < 2; ++h)
                pf[i][h] = *(const bf16x8*)&sp[i * 16 + lo][h * 32 + quad * 8];
        // AV: accO[i][cs] -> lane holds (n = n0w+i*16+quad*4+rg, c = cs*16+lo)
#pragma unroll
        for (int i = 0; i < 2; ++i)
#pragma unroll
            for (int cs = 0; cs < 4; ++cs) {
                accO[i][cs] = __builtin_amdgcn_mfma_f32_16x16x32_bf16(pf[i][0], gb[cs][0], accO[i][cs], 0, 0, 0);
                accO[i][cs] = __builtin_amdgcn_mfma_f32_16x16x32_bf16(pf[i][1], gb[cs][1], accO[i][cs], 0, 0, 0);
            }
        __syncthreads();   // stage(ch+1) complete + buffer reuse safe
        buf ^= 1;
    }
#undef STAGE
    // l: full in-wave reduction (lane j holds l[n = i*16 + (j&15)])
#pragma unroll
    for (int i = 0; i < 2; ++i) {
        lsum[i] += __shfl_xor(lsum[i], 16, 64);
        lsum[i] += __shfl_xor(lsum[i], 32, 64);
    }
    if (split) {
        float* np = PNUM + ((size_t)((seg * 4 + p) * 72 + r)) * 8192;
        float* lp = PL + ((size_t)((seg * 4 + p) * 72 + r)) * 128;
        if (quad == 0) {
            lp[w * 32 + lo] = lsum[0];
            lp[w * 32 + 16 + lo] = lsum[1];
        }
#pragma unroll
        for (int i = 0; i < 2; ++i)
#pragma unroll
            for (int cs = 0; cs < 4; ++cs)
#pragma unroll
                for (int rg = 0; rg < 4; ++rg) {
                    int nl = w * 32 + i * 16 + quad * 4 + rg;
                    np[nl * 64 + cs * 16 + lo] = accO[i][cs][rg];
                }
    } else {
        short* outm = OUTb + (size_t)seg * 589824;
#pragma unroll
        for (int i = 0; i < 2; ++i)
#pragma unroll
            for (int rg = 0; rg < 4; ++rg) {
                float lt = __shfl(lsum[i], quad * 4 + rg, 64);
                int n = n0w + i * 16 + quad * 4 + rg;
#pragma unroll
                for (int cs = 0; cs < 4; ++cs)
                    outm[((size_t)b * NN + n) * 64 + cs * 16 + lo] = f2b(accO[i][cs][rg] / lt);
            }
    }
}

// ---------------- K3: MFMA z-conv + BN partial stats, FUSED attn-combine ------
__global__ __launch_bounds__(256) void k_z(const short* __restrict__ OUTb,
                                           const float* __restrict__ z_w,
                                           const float* __restrict__ PNUM,
                                           const float* __restrict__ PL,
                                           short* __restrict__ Zb,
                                           float* __restrict__ PART) {
    __shared__ __align__(16) short s_ut[64][72];
    int t = threadIdx.x;
    int seg = blockIdx.x / 144;
    int r = blockIdx.x % 144;
    int b = r / 36;
    int sp0 = (r % 36) * 64;
    short* z = Zb + (size_t)seg * 2359296 + (size_t)b * 589824;
    float* part = PART + (size_t)(seg * 144 + r) * 512;

    int w = t >> 6, lane = t & 63, lo = lane & 15, quad = lane >> 4;

    bf16x8 af[4][2];
#pragma unroll
    for (int qt = 0; qt < 4; ++qt)
#pragma unroll
        for (int h = 0; h < 2; ++h)
            af[qt][h] = ld8cvt(&z_w[(size_t)(w * 64 + qt * 16 + lo) * 64 + h * 32 + quad * 8]);

    if (seg < 2) {
        int sp036 = r % 36;
#pragma unroll
        for (int rr = 0; rr < 4; ++rr) {
            int idx = t + rr * 256;
            int spl = idx & 63;
            int cp0 = (idx >> 6) << 2;
            short4 pk;
#pragma unroll
            for (int j = 0; j < 4; ++j) {
                int ng = (cp0 + j) * 36 + sp036;
                int rb = b * 18 + (ng >> 7);
                int nl = ng & 127;
                float num = 0.f, l = 0.f;
#pragma unroll
                for (int pp = 0; pp < 4; ++pp) {
                    size_t base = (size_t)((seg * 4 + pp) * 72 + rb);
                    num += PNUM[base * 8192 + nl * 64 + spl];
                    l   += PL[base * 128 + nl];
                }
                ((short*)&pk)[j] = f2b(num / l);
            }
            *(short4*)&s_ut[spl][cp0] = pk;
        }
    } else {
        const short* F = OUTb + (size_t)seg * 589824 + (size_t)b * 147456;
#pragma unroll
        for (int rr = 0; rr < 4; ++rr) {
            int idx = t + rr * 256;
            int spl = idx & 63;
            int cp0 = (idx >> 6) << 2;
            short4 pk;
            pk.x = F[(size_t)(cp0 + 0) * 2304 + sp0 + spl];
            pk.y = F[(size_t)(cp0 + 1) * 2304 + sp0 + spl];
            pk.z = F[(size_t)(cp0 + 2) * 2304 + sp0 + spl];
            pk.w = F[(size_t)(cp0 + 3) * 2304 + sp0 + spl];
            *(short4*)&s_ut[spl][cp0] = pk;
        }
    }
    __syncthreads();

    bf16x8 bfr[4][2];
#pragma unroll
    for (int st = 0; st < 4; ++st)
#pragma unroll
        for (int h = 0; h < 2; ++h)
            bfr[st][h] = *(const bf16x8*)&s_ut[st * 16 + lo][h * 32 + quad * 8];

    f32x4 acc[4][4];
#pragma unroll
    for (int qt = 0; qt < 4; ++qt)
#pragma unroll
        for (int st = 0; st < 4; ++st) {
            acc[qt][st] = f32x4{0.f, 0.f, 0.f, 0.f};
            acc[qt][st] = __builtin_amdgcn_mfma_f32_16x16x32_bf16(af[qt][0], bfr[st][0], acc[qt][st], 0, 0, 0);
            acc[qt][st] = __builtin_amdgcn_mfma_f32_16x16x32_bf16(af[qt][1], bfr[st][1], acc[qt][st], 0, 0, 0);
        }

#pragma unroll
    for (int qt = 0; qt < 4; ++qt) {
        float s1[4] = {0.f, 0.f, 0.f, 0.f};
        float s2[4] = {0.f, 0.f, 0.f, 0.f};
        int qb = w * 64 + qt * 16 + quad * 4;
#pragma unroll
        for (int st = 0; st < 4; ++st) {
            int sp = sp0 + st * 16 + lo;
#pragma unroll
            for (int rg = 0; rg < 4; ++rg) {
                float v = acc[qt][st][rg];
                z[(size_t)(qb + rg) * 2304 + sp] = f2b(v);
                s1[rg] += v;
                s2[rg] += v * v;
            }
        }
#pragma unroll
        for (int rg = 0; rg < 4; ++rg) {
            for (int o = 8; o >= 1; o >>= 1) {
                s1[rg] += __shfl_xor(s1[rg], o, 16);
                s2[rg] += __shfl_xor(s2[rg], o, 16);
            }
            if (lo == 0) {
                float2 v2; v2.x = s1[rg]; v2.y = s2[rg];
                *(float2*)&part[(size_t)(qb + rg) * 2] = v2;
            }
        }
    }
}

// ---------------- K4: final BN-normalize-and-sum, FUSED stats reduce ----------
// k_stats kernel eliminated: each block needs at most 2 distinct channels q
// (1024 contiguous elements vs 2304-element rows) x 5 segs = 10 (seg,q) stat
// pairs. 160 threads cooperatively sum the 144 per-block partials per pair
// (PART is 1.5MB -> L2/L3-resident), 16-wide shfl reduce, broadcast via LDS.
__global__ __launch_bounds__(256) void k_final(
    const short* __restrict__ Zb, const float* __restrict__ PART,
    const float* g0, const float* g1, const float* g2, const float* g3, const float* g4,
    const float* b0, const float* b1, const float* b2, const float* b3, const float* b4,
    float* __restrict__ outp) {
    __shared__ float s_st[10][2];
    int tid = threadIdx.x;
    int base = blockIdx.x * 1024;                 // first element of this block
    int qA = (base / NN) & 255;
    int qB = ((base + 1023) / NN) & 255;
    if (tid < 160) {
        int c = tid >> 4;     // 0..9 : seg = c>>1, q = (c&1)? qB : qA
        int k = tid & 15;     // 0..15, sums 9 of the 144 partials
        int i = c >> 1;
        int q = (c & 1) ? qB : qA;
        const float* p = PART + (size_t)i * 144 * 512 + q * 2;
        float s1 = 0.f, s2 = 0.f;
#pragma unroll
        for (int j = 0; j < 9; ++j) {
            float2 v = *(const float2*)&p[(size_t)(k * 9 + j) * 512];
            s1 += v.x; s2 += v.y;
        }
        for (int o = 8; o >= 1; o >>= 1) {
            s1 += __shfl_down(s1, o, 16);
            s2 += __shfl_down(s2, o, 16);
        }
        if (k == 0) { s_st[c][0] = s1; s_st[c][1] = s2; }
    }
    __syncthreads();

    int idx4 = base + tid * 4;
    int q = (idx4 / NN) & 255;
    int sel = (q == qA) ? 0 : 1;
    const float inv = 1.f / (float)(BB * NN);
    float4 o = {0.f, 0.f, 0.f, 0.f};
#pragma unroll
    for (int i = 0; i < 5; ++i) {
        float mean = s_st[i * 2 + sel][0] * inv;
        float var = s_st[i * 2 + sel][1] * inv - mean * mean;
        float rr = rsqrtf(var + 1e-5f);
        const float* gm = (i == 0) ? g0 : (i == 1) ? g1 : (i == 2) ? g2 : (i == 3) ? g3 : g4;
        const float* bt = (i == 0) ? b0 : (i == 1) ? b1 : (i == 2) ? b2 : (i == 3) ? b3 : b4;
        float sc = rr * gm[q];
        float ofs = bt[q] - mean * sc;
        short4 zv = *(const short4*)&Zb[(size_t)i * 2359296 + idx4];
        o.x += b2f16(zv.x) * sc + ofs;
        o.y += b2f16(zv.y) * sc + ofs;
        o.z += b2f16(zv.z) * sc + ofs;
        o.w += b2f16(zv.w) * sc + ofs;
    }
    *(float4*)&outp[idx4] = o;
}

extern "C" void kernel_launch(void* const* d_in, const int* in_sizes, int n_in,
                              void* d_out, int out_size, void* d_ws, size_t ws_size,
                              hipStream_t stream) {
    const float* persp = (const float*)d_in[0];
    const float* resp[5];
    for (int i = 0; i < 5; ++i) resp[i] = (const float*)d_in[1 + i];
    const float* t_w = (const float*)d_in[6];
    const float* z_w = (const float*)d_in[7];
    const float *p_w[5], *g_w[5], *bng[5], *bnb[5];
    for (int i = 0; i < 5; ++i) {
        p_w[i] = (const float*)d_in[8 + 4 * i];
        g_w[i] = (const float*)d_in[9 + 4 * i];
        bng[i] = (const float*)d_in[10 + 4 * i];
        bnb[i] = (const float*)d_in[11 + 4 * i];
    }
    // workspace layout (~61 MB total)
    short* TQb  = (short*)d_ws;             // 589,824
    short* TWb  = TQb + 589824;             // 16,384
    short* WPb  = TWb + 16384;              // 249,856
    short* WGb  = WPb + 249856;             // 249,856
    short* PTb  = WGb + 249856;             // 1,392,640
    short* GTb  = PTb + 1392640;            // 1,392,640
    short* Zb   = GTb + 1392640;            // 11,796,480
    short* OUTb = Zb + 11796480;            // 2,949,120  (only segs 2-4 used)
    float* PPART = (float*)(OUTb + 2949120);  // 622,592 (split-K partials; reused as BN partials by k_z)
    float* GPART = PPART + 622592;          // 622,592
    float* PNUM  = GPART + 622592;          // 4,718,592 (attn split-m numerators)
    float* PL    = PNUM + 4718592;          // 73,728    (attn split-m denominators)

    k_wcvt<<<2016, 256, 0, stream>>>(t_w,
        p_w[0], p_w[1], p_w[2], p_w[3], p_w[4],
        g_w[0], g_w[1], g_w[2], g_w[3], g_w[4],
        TWb, WPb, WGb);
    k_conv<<<584, 256, 0, stream>>>(persp,
        resp[0], resp[1], resp[2], resp[3], resp[4],
        TWb, WPb, WGb, TQb, PTb, GTb, PPART, GPART);
    k_cvt<<<832, 256, 0, stream>>>(PPART, GPART, PTb, GTb);
    k_attn<<<792, 256, 0, stream>>>(TQb, PTb, GTb, OUTb, PNUM, PL);
    k_z<<<720, 256, 0, stream>>>(OUTb, z_w, PNUM, PL, Zb, PPART);
    k_final<<<2304, 256, 0, stream>>>(Zb, PPART,
        bng[0], bng[1], bng[2], bng[3], bng[4],
        bnb[0], bnb[1], bnb[2], bnb[3], bnb[4],
        (float*)d_out);
}